// Round 1
// baseline (364.618 us; speedup 1.0000x reference)
//
#include <hip/hip_runtime.h>

typedef short bf16x8 __attribute__((ext_vector_type(8)));
typedef short bf16x4 __attribute__((ext_vector_type(4)));
typedef float f32x4  __attribute__((ext_vector_type(4)));
typedef unsigned int u32x2 __attribute__((ext_vector_type(2)));

#define HID 128
#define TT 32
#define HWSZ 1024
#define PX 32
#define NTHREADS 512

__device__ __forceinline__ unsigned short f2bf(float f) {
    union { float f; unsigned int i; } v; v.f = f;
    unsigned int u = v.i;
    return (unsigned short)((u + 0x7fffu + ((u >> 16) & 1u)) >> 16);
}
__device__ __forceinline__ unsigned int cvt_pk_bf16(float lo, float hi) {
    unsigned int r;
    asm("v_cvt_pk_bf16_f32 %0, %1, %2" : "=v"(r) : "v"(lo), "v"(hi));
    return r;
}
__device__ __forceinline__ float frcp(float x) { return __builtin_amdgcn_rcpf(x); }
__device__ __forceinline__ float sigm(float x) { return frcp(1.0f + __expf(-x)); }
__device__ __forceinline__ float ftanh(float x){ return 1.0f - 2.0f * frcp(1.0f + __expf(2.0f * x)); }

// One block = PX=32 pixels for the whole sequence; 8 waves; wave w owns
// hidden channels [16w,16w+16) x 4 gates. A = W rows (regs), B = pixels (LDS),
// D reg-dim = channel -> direct register y/hT/cT stores, packed b64 h-writeback.
//
// Step pipeline: gates(t) = Wx*x_t + Wh*h_{t-1}. The x-part for step t+1 is
// computed DURING step t (x triple-buffered in LDS, staged two steps ahead),
// carried across the barrier in a second accumulator set. Bias is folded into
// the accumulator init. Barrier is lgkmcnt-only (global ops stay in flight).
// LDS row (per px): [x s0 | x s1 | x s2 | h0 | h1 | pad 8].
template <int CIN, bool FINAL, bool IN_LOCAL, bool OUT_LOCAL>
__global__ __launch_bounds__(NTHREADS, 2)
void lstm_layer(const void* __restrict__ in_, const float* __restrict__ W,
                const float* __restrict__ bias, void* __restrict__ y_,
                float* __restrict__ hT, float* __restrict__ cT)
{
    constexpr int K      = CIN + HID;
    constexpr int XK     = CIN / 32;           // x-part k-iters
    constexpr int HK     = HID / 32;           // h-part k-iters
    constexpr int KITERS = K / 32;
    constexpr int HB0 = 3 * CIN, HB1 = 3 * CIN + HID;
    constexpr int PITCH = 3 * CIN + 2 * HID + 8;   // bytes/row mult. of 16
    constexpr int NIT = (PX * CIN / 4) / NTHREADS; // fp32-in iters (1 or 2)

    const float* inF          = (const float*)in_;
    const unsigned short* inL = (const unsigned short*)in_;
    float* yF                 = (float*)y_;
    unsigned short* yL        = (unsigned short*)y_;

    __shared__ __align__(16) unsigned short z[PX][PITCH];

    const int tid  = threadIdx.x;
    const int wave = tid >> 6;
    const int lane = tid & 63;
    const int q    = lane >> 4;
    const int ln   = lane & 15;

    const int p0  = blockIdx.x * PX;
    const int b   = p0 >> 10;
    const int hw0 = p0 & 1023;

    const long long locbase = (long long)blockIdx.x * TT * PX * HID;  // local scratch
    const long long inFbase = (long long)b * TT * CIN * HWSZ + hw0;   // fp32 [c][hw]

    // ---- preload W fragments (A operand): rows = gate tiles
    bf16x8 Af[KITERS][4];
    #pragma unroll
    for (int k = 0; k < KITERS; ++k) {
        #pragma unroll
        for (int g = 0; g < 4; ++g) {
            const float* wp = W + (g * HID + wave * 16 + ln) * K + k * 32 + q * 8;
            bf16x8 v;
            #pragma unroll
            for (int j = 0; j < 8; ++j) v[j] = (short)f2bf(wp[j]);
            Af[k][g] = v;
        }
    }
    // bias: lane's 4 consecutive channels per gate (folded into acc init)
    f32x4 bs[4];
    #pragma unroll
    for (int g = 0; g < 4; ++g)
        bs[g] = *(const f32x4*)(bias + g * HID + wave * 16 + q * 4);

    const int ch0 = wave * 16 + q * 4;   // lane's first channel
    float* const ybase = yF + ((long long)b * TT * HID + ch0) * HWSZ + hw0;

    // ---- zero h buf0; stage x_0 -> slot0, x_1 -> slot1
    #pragma unroll
    for (int idx = tid; idx < PX * HID; idx += NTHREADS)
        z[idx & (PX - 1)][HB0 + (idx >> 5)] = 0;
    if (IN_LOCAL) {
        bf16x8 v0 = *(const bf16x8*)(inL + locbase + tid * 8);
        bf16x8 v1 = *(const bf16x8*)(inL + locbase + (long long)PX * HID + tid * 8);
        *(bf16x8*)&z[tid >> 4][(tid & 15) * 8] = v0;
        *(bf16x8*)&z[tid >> 4][CIN + (tid & 15) * 8] = v1;
    } else {
        #pragma unroll
        for (int it = 0; it < NIT; ++it) {
            const int idx = tid + it * NTHREADS;
            const int pxs = idx & 31, c0 = (idx >> 5) * 4;
            float a0[4], a1[4];
            #pragma unroll
            for (int j = 0; j < 4; ++j) a0[j] = inF[inFbase + (c0 + j) * HWSZ + pxs];
            #pragma unroll
            for (int j = 0; j < 4; ++j) a1[j] = inF[inFbase + (long long)CIN * HWSZ + (c0 + j) * HWSZ + pxs];
            u32x2 v0, v1;
            v0[0] = cvt_pk_bf16(a0[0], a0[1]); v0[1] = cvt_pk_bf16(a0[2], a0[3]);
            v1[0] = cvt_pk_bf16(a1[0], a1[1]); v1[1] = cvt_pk_bf16(a1[2], a1[3]);
            *(u32x2*)&z[pxs][c0] = v0;
            *(u32x2*)&z[pxs][CIN + c0] = v1;
        }
    }
    __syncthreads();

    float cst[2][4];
    #pragma unroll
    for (int mt = 0; mt < 2; ++mt)
        #pragma unroll
        for (int r = 0; r < 4; ++r) cst[mt][r] = 0.0f;

    f32x4 accA[2][4], accB[2][4];
    // prologue: accA = bias + Wx * x_0 (slot 0)
    #pragma unroll
    for (int g = 0; g < 4; ++g) { accA[0][g] = bs[g]; accA[1][g] = bs[g]; }
    #pragma unroll
    for (int k = 0; k < XK; ++k) {
        const int koff = k * 32;
        const bf16x8 pv0 = *(const bf16x8*)&z[ln][koff + q * 8];
        const bf16x8 pv1 = *(const bf16x8*)&z[16 + ln][koff + q * 8];
        #pragma unroll
        for (int g = 0; g < 4; ++g) {
            accA[0][g] = __builtin_amdgcn_mfma_f32_16x16x32_bf16(Af[k][g], pv0, accA[0][g], 0, 0, 0);
            accA[1][g] = __builtin_amdgcn_mfma_f32_16x16x32_bf16(Af[k][g], pv1, accA[1][g], 0, 0, 0);
        }
    }

// One LSTM step: finish gates(T) with the h-part into ACCC, prefetch x_{T+2},
// start ACCN = bias + Wx*x_{T+1}, pointwise, write h/x to LDS, light barrier.
#define LSTM_STEP(T, PAR, ACCC, ACCN)                                            \
    {                                                                            \
        const int hb_r = (PAR) ? HB1 : HB0;                                      \
        const int hb_w = (PAR) ? HB0 : HB1;                                      \
        const int xs_n = ((T) + 1) % 3;                                          \
        const int xs_w = ((T) + 2) % 3;                                          \
        const int tn2  = ((T) + 2 < TT) ? (T) + 2 : TT - 1;                      \
        bf16x8 pfv; float pff[NIT][4];                                           \
        if (IN_LOCAL) {                                                          \
            pfv = *(const bf16x8*)(inL + locbase + (long long)tn2 * PX * HID + tid * 8); \
        } else {                                                                 \
            _Pragma("unroll")                                                    \
            for (int it = 0; it < NIT; ++it) {                                   \
                const int idx = tid + it * NTHREADS;                             \
                const int pxs = idx & 31, c0 = (idx >> 5) * 4;                   \
                _Pragma("unroll")                                                \
                for (int j = 0; j < 4; ++j)                                      \
                    pff[it][j] = inF[inFbase + (long long)tn2 * CIN * HWSZ + (c0 + j) * HWSZ + pxs]; \
            }                                                                    \
        }                                                                        \
        _Pragma("unroll")                                                        \
        for (int k = 0; k < HK; ++k) {                                           \
            const int koff = hb_r + k * 32;                                      \
            const bf16x8 pv0 = *(const bf16x8*)&z[ln][koff + q * 8];             \
            const bf16x8 pv1 = *(const bf16x8*)&z[16 + ln][koff + q * 8];        \
            _Pragma("unroll")                                                    \
            for (int g = 0; g < 4; ++g) {                                        \
                ACCC[0][g] = __builtin_amdgcn_mfma_f32_16x16x32_bf16(Af[XK + k][g], pv0, ACCC[0][g], 0, 0, 0); \
                ACCC[1][g] = __builtin_amdgcn_mfma_f32_16x16x32_bf16(Af[XK + k][g], pv1, ACCC[1][g], 0, 0, 0); \
            }                                                                    \
        }                                                                        \
        _Pragma("unroll")                                                        \
        for (int g = 0; g < 4; ++g) { ACCN[0][g] = bs[g]; ACCN[1][g] = bs[g]; }  \
        _Pragma("unroll")                                                        \
        for (int k = 0; k < XK; ++k) {                                           \
            const int koff = xs_n * CIN + k * 32;                                \
            const bf16x8 pv0 = *(const bf16x8*)&z[ln][koff + q * 8];             \
            const bf16x8 pv1 = *(const bf16x8*)&z[16 + ln][koff + q * 8];        \
            _Pragma("unroll")                                                    \
            for (int g = 0; g < 4; ++g) {                                        \
                ACCN[0][g] = __builtin_amdgcn_mfma_f32_16x16x32_bf16(Af[k][g], pv0, ACCN[0][g], 0, 0, 0); \
                ACCN[1][g] = __builtin_amdgcn_mfma_f32_16x16x32_bf16(Af[k][g], pv1, ACCN[1][g], 0, 0, 0); \
            }                                                                    \
        }                                                                        \
        _Pragma("unroll")                                                        \
        for (int mt = 0; mt < 2; ++mt) {                                         \
            const int px = mt * 16 + ln;                                         \
            float hr[4];                                                         \
            _Pragma("unroll")                                                    \
            for (int r = 0; r < 4; ++r) {                                        \
                const float iv = sigm(ACCC[mt][0][r]);                           \
                const float fv = sigm(ACCC[mt][1][r]);                           \
                const float ov = sigm(ACCC[mt][2][r]);                           \
                const float gv = ftanh(ACCC[mt][3][r]);                          \
                const float c  = fv * cst[mt][r] + iv * gv;                      \
                cst[mt][r] = c;                                                  \
                hr[r] = ov * ftanh(c);                                           \
                if (FINAL && (T) == TT - 1)                                      \
                    cT[((long long)(b * HID + ch0 + r)) * HWSZ + hw0 + px] = c;  \
            }                                                                    \
            u32x2 hv;                                                            \
            hv[0] = cvt_pk_bf16(hr[0], hr[1]);                                   \
            hv[1] = cvt_pk_bf16(hr[2], hr[3]);                                   \
            *(u32x2*)&z[px][hb_w + ch0] = hv;                                    \
            if (FINAL || !OUT_LOCAL) {                                           \
                float* yp = ybase + (long long)(T) * (HID * HWSZ) + px;          \
                yp[0] = hr[0]; yp[HWSZ] = hr[1];                                 \
                yp[2 * HWSZ] = hr[2]; yp[3 * HWSZ] = hr[3];                      \
                if (FINAL && (T) == TT - 1) {                                    \
                    float* hp = hT + ((long long)(b * HID + ch0)) * HWSZ + hw0 + px; \
                    hp[0] = hr[0]; hp[HWSZ] = hr[1];                             \
                    hp[2 * HWSZ] = hr[2]; hp[3 * HWSZ] = hr[3];                  \
                }                                                                \
            }                                                                    \
        }                                                                        \
        if (IN_LOCAL) {                                                          \
            *(bf16x8*)&z[tid >> 4][xs_w * CIN + (tid & 15) * 8] = pfv;           \
        } else {                                                                 \
            _Pragma("unroll")                                                    \
            for (int it = 0; it < NIT; ++it) {                                   \
                const int idx = tid + it * NTHREADS;                             \
                const int pxs = idx & 31, c0 = (idx >> 5) * 4;                   \
                u32x2 xv;                                                        \
                xv[0] = cvt_pk_bf16(pff[it][0], pff[it][1]);                     \
                xv[1] = cvt_pk_bf16(pff[it][2], pff[it][3]);                     \
                *(u32x2*)&z[pxs][xs_w * CIN + c0] = xv;                          \
            }                                                                    \
        }                                                                        \
        asm volatile("s_waitcnt lgkmcnt(0)\n\ts_barrier" ::: "memory");          \
        if (!FINAL && OUT_LOCAL) {                                               \
            bf16x8 hv8 = *(const bf16x8*)&z[tid >> 4][hb_w + (tid & 15) * 8];    \
            *(bf16x8*)(yL + locbase + (long long)(T) * PX * HID + tid * 8) = hv8; \
        }                                                                        \
    }

    for (int t = 0; t < TT; t += 2) {
        LSTM_STEP(t,     0, accA, accB)
        LSTM_STEP(t + 1, 1, accB, accA)
    }
#undef LSTM_STEP
}

extern "C" void kernel_launch(void* const* d_in, const int* in_sizes, int n_in,
                              void* d_out, int out_size, void* d_ws, size_t ws_size,
                              hipStream_t stream) {
    const float* x  = (const float*)d_in[0];
    const float* W0 = (const float*)d_in[1];
    const float* b0 = (const float*)d_in[2];
    const float* W1 = (const float*)d_in[3];
    const float* b1 = (const float*)d_in[4];
    float* out = (float*)d_out;

    float* y  = out;                      // [8,32,128,32,32] fp32
    float* hT = out + 33554432;           // [8,128,32,32]
    float* cT = out + 34603008;           // [8,128,32,32]

    dim3 grid(8192 / PX), block(NTHREADS);

    const size_t y0_bytes = (size_t)8 * HWSZ * TT * HID * 2;  // 67 MB block-local bf16
    if (ws_size >= y0_bytes) {
        unsigned short* y0 = (unsigned short*)d_ws;
        lstm_layer<64,  false, false, true ><<<grid, block, 0, stream>>>(x,  W0, b0, y0, nullptr, nullptr);
        lstm_layer<128, true,  true,  false><<<grid, block, 0, stream>>>(y0, W1, b1, y,  hT, cT);
    } else {
        // fallback: y0 fp32 [b][t][c][hw] in-place in the y region (reads are
        // always >= 2 steps ahead of writes within a block; layers separate)
        lstm_layer<64,  false, false, false><<<grid, block, 0, stream>>>(x, W0, b0, y, nullptr, nullptr);
        lstm_layer<128, true,  false, false><<<grid, block, 0, stream>>>(y, W1, b1, y, hT, cT);
    }
}